// Round 12
// baseline (269.740 us; speedup 1.0000x reference)
//
#include <hip/hip_runtime.h>
#include <cstdint>
#include <cstddef>

// ---------------------------------------------------------------------------
// Zoner: out = softmax( mask ? -inf : tanh(zone@Wz+bz) . tanh(mean(txt)@Wt+bt) / sqrt(768) )
// B=32 L=80 Z=4096 D=768 DO=256.  Dominant cost: 402MB zone read.
// Best: R7/R11 = 152-153us. GEMM read stream invariant at ~3.0-3.2 TB/s across
// 6 design axes; pure-write fills do 6.7 TB/s. Last live hypothesis: VGPR-
// capped occupancy (acc32+breg32+va16+addr ~95 regs -> 16 waves/CU) limits
// read-stream TLP.
// R12 = R11 with B SINGLE-buffered (load at point of use; L2-hot, latency
// hidden across waves) saving 16 VGPR, + __launch_bounds__(512,6) ->
// 3 blocks/CU = 24 waves/CU. Single-variable TLP experiment.
// ---------------------------------------------------------------------------

typedef float  f32x4  __attribute__((ext_vector_type(4)));
typedef __bf16 bf16x4 __attribute__((ext_vector_type(4)));
typedef __bf16 bf16x8 __attribute__((ext_vector_type(8)));

// workspace layout (bytes)
#define OFF_T     0         // t[32][256] fp32          (32 KB)
#define OFF_WZT   32768     // WzT fragment-order bf16, 196608 elems (384 KB)
#define OFF_FLAG  425984    // mask-format flag (int)
#define OFF_MP    426240    // mean partials [32][8][768] fp32 (768 KB)

__device__ __forceinline__ float fast_tanh(float x) {
    x = fminf(15.f, fmaxf(-15.f, x));
    float e2 = __expf(2.f * x);
    return (e2 - 1.f) * __builtin_amdgcn_rcpf(e2 + 1.f);
}

// ---------------------------------------------------------------------------
// prep1: blocks 0..255   : txt mean partial sums (b = blk>>3, 10 L-slices each)
//        blocks 256..319 : Wz -> fragment-order wzt
//          wzt[((kt*2+h)*16+g)*512 + lane*8 + e] = bf16(Wz[k][n])
//          with n = g*16 + (lane&15), k = kt*64 + h*32 + (lane>>4)*8 + e.
//        block  320      : mask dtype detector -> flag {0:int32,1:bytes,2:fp32,3:int64}
// ---------------------------------------------------------------------------
__global__ void prep1_kernel(const float* __restrict__ txt,
                             const float* __restrict__ Wz,
                             const void*  __restrict__ mask,
                             float* __restrict__ mp,
                             unsigned short* __restrict__ wzt,
                             int* __restrict__ flagp)
{
    const int blk = blockIdx.x, tid = threadIdx.x;
    if (blk < 256) {
        const int b = blk >> 3, part = blk & 7;
        const float* base = txt + (size_t)(b * 80 + part * 10) * 768;
        for (int d = tid; d < 768; d += 256) {
            float s = 0.f;
            #pragma unroll
            for (int l = 0; l < 10; ++l) s += base[l * 768 + d];
            mp[(b * 8 + part) * 768 + d] = s;
        }
    } else if (blk < 320) {
        const int i0 = (blk - 256) * 3072;
        for (int it = 0; it < 12; ++it) {
            int idx  = i0 + it * 256 + tid;      // 0..196607
            int e    = idx & 7;
            int lane = (idx >> 3) & 63;
            int slot = idx >> 9;                 // (kt*2+h)*16 + g
            int kt   = slot >> 5;
            int h    = (slot >> 4) & 1;
            int g    = slot & 15;
            int n    = g * 16 + (lane & 15);
            int k    = kt * 64 + h * 32 + (lane >> 4) * 8 + e;
            __bf16 v = (__bf16)Wz[k * 256 + n];
            wzt[idx] = __builtin_bit_cast(unsigned short, v);
        }
    } else {
        // scan first 32768 bytes (valid window for every candidate dtype)
        const unsigned* mw = (const unsigned*)mask;
        unsigned f_isf = 0, f_gt = 0, f_onz = 0, f_nz = 0;
        for (int i = tid; i < 8192; i += 256) {
            unsigned w = mw[i];
            if (w == 0x3F800000u) f_isf = 1;   // float 1.0 pattern
            else if (w > 1u)      f_gt  = 1;   // packed bool bytes
            if (w) { f_nz = 1; if (i & 1) f_onz = 1; }
        }
        __shared__ unsigned r[4];
        if (tid < 4) r[tid] = 0;
        __syncthreads();
        if (f_isf) atomicOr(&r[0], 1u);
        if (f_gt)  atomicOr(&r[1], 1u);
        if (f_onz) atomicOr(&r[2], 1u);
        if (f_nz)  atomicOr(&r[3], 1u);
        __syncthreads();
        if (tid == 0) {
            int flag;
            if (r[0])        flag = 2;   // fp32 0/1
            else if (r[1])   flag = 1;   // bytes
            else if (!r[3])  flag = 1;   // all-zero: byte path is always safe
            else if (!r[2])  flag = 3;   // nonzeros but all odd words zero -> int64
            else             flag = 0;   // int32
            *flagp = flag;
        }
    }
}

// ---------------------------------------------------------------------------
// prep2: mean = sum(partials)/80 ; t[b][o] = tanh(mean @ Wt + bt)   (fp32)
// ---------------------------------------------------------------------------
__global__ void prep2_kernel(const float* __restrict__ mp,
                             const float* __restrict__ Wt,
                             const float* __restrict__ bt,
                             float* __restrict__ tws)
{
    const int b = blockIdx.x, tid = threadIdx.x;
    __shared__ float meanv[768];
    for (int d = tid; d < 768; d += 256) {
        float s = 0.f;
        #pragma unroll
        for (int p = 0; p < 8; ++p) s += mp[(b * 8 + p) * 768 + d];
        meanv[d] = s * 0.0125f;   // 1/80
    }
    __syncthreads();
    float acc = bt[tid];
    for (int d = 0; d < 768; ++d) acc = fmaf(meanv[d], Wt[d * 256 + tid], acc);
    tws[b * 256 + tid] = tanhf(acc);
}

// ---------------------------------------------------------------------------
// Fused GEMM (R7 core, B single-buffered) + XCD-chunk swizzle.
// BM=64 rows/block, N=256, K=768 (12 steps), 512 thr / 8 waves; wave wv owns
// 64 rows x cols [wv*32,+32): acc[4][2]. A: fp32->bf16 reg-staged into
// XOR-swizzled LDS (2x8KB dbuf), 2-deep reg prefetch. B: fragment-order wzt,
// coalesced 1KB wave reads at POINT OF USE (single buffer, L2-hot).
// Sync: raw s_barrier + lgkmcnt(0); vmcnt never drained.
// __launch_bounds__(512,6): ~80 VGPR target -> 3 blocks/CU (24 waves).
// ---------------------------------------------------------------------------
__global__ __launch_bounds__(512, 6)
void gemm_kernel(const float* __restrict__ zone,
                 const unsigned short* __restrict__ wzt,   // fragment-order B
                 const float* __restrict__ tws,
                 const float* __restrict__ bz,
                 float* __restrict__ out)
{
    __shared__ alignas(16) unsigned char smem[16384];   // A double buffer only
    const int tid  = threadIdx.x;
    // XCD-chunk swizzle (bijective, 2048 % 8 == 0): each XCD streams a
    // contiguous zone region.
    const int orig = blockIdx.x;
    const int blk  = (orig & 7) * 256 + (orig >> 3);
    const int rowbase = blk << 6;          // 64 rows per block
    const int b    = blk >> 6;             // batch (64 blocks each)
    const int lane = tid & 63;
    const int wv   = tid >> 6;             // wave 0..7; cols wv*32..wv*32+31
    const int l15  = lane & 15;
    const int l4   = lane >> 4;

    // A fragment LDS addresses (rows of 128B, XOR-swizzled 16B chunks by row&7)
    const int swz = (l15 & 7) << 4;
    const int kb0 = (l4 * 16) ^ swz;             // k 0..31
    const int kb1 = (64 + l4 * 16) ^ swz;        // k 32..63

    // A staging: 1024 8B-chunks; thread t handles chunks t and t+512.
    const int sg_r0 = tid >> 4;                  // rows 0..31 (i=0) / +32 (i=1)
    const int sg_c4 = tid & 15;
    const int sg_kb = (sg_c4 * 8) ^ ((sg_r0 & 7) << 4);   // (row+32)&7 == row&7

    // B fragment base: coalesced — lane's 16B chunk within each 1KB slot
    const unsigned short* Bg = wzt + (size_t)lane * 8;

    f32x4 acc[4][2];
    #pragma unroll
    for (int i = 0; i < 4; ++i)
        #pragma unroll
        for (int j = 0; j < 2; ++j)
            acc[i][j] = f32x4{0.f, 0.f, 0.f, 0.f};

    const float* Ag = zone + (size_t)rowbase * 768;

    f32x4  va[2][2];          // A 2-deep register prefetch (fp32)

    auto load_a = [&](int kt, f32x4* v) {
        const float* Agk = Ag + kt * 64 + sg_c4 * 4;
        v[0] = *(const f32x4*)(Agk + (size_t)sg_r0 * 768);
        v[1] = *(const f32x4*)(Agk + (size_t)(sg_r0 + 32) * 768);
    };
    auto write_a = [&](int buf, const f32x4* v) {
        #pragma unroll
        for (int i = 0; i < 2; ++i) {
            bf16x4 h = { (__bf16)v[i][0], (__bf16)v[i][1], (__bf16)v[i][2], (__bf16)v[i][3] };
            *(bf16x4*)(smem + buf * 8192 + (i * 32 + sg_r0) * 128 + sg_kb) = h;
        }
    };

    // ---- prologue (invariant: va[cur]==A(kt+1)) ----
    load_a(0, va[1]);             // A(0) temp
    write_a(0, va[1]);            // compiler waits exactly for va[1]
    load_a(1, va[0]);             // A(1) stays in flight across barrier
    asm volatile("s_waitcnt lgkmcnt(0)" ::: "memory");
    __builtin_amdgcn_s_barrier();
    __builtin_amdgcn_sched_barrier(0);

    // ---- main K loop (fully unrolled; all indices compile-time) ----
    #pragma unroll
    for (int kt = 0; kt < 12; ++kt) {
        const int cur = kt & 1;
        if (kt < 10) {
            load_a(kt + 2, va[cur ^ 1]);         // A(kt+2): newest in queue
            __builtin_amdgcn_sched_barrier(0);   // pin issue at phase top
        }
        // B for this k-step: issue loads (L2-hot), then A frags from LDS[cur]
        {
            bf16x8 breg[2][2];
            #pragma unroll
            for (int nt = 0; nt < 2; ++nt)
                #pragma unroll
                for (int h = 0; h < 2; ++h) {
                    const int slot = (kt * 2 + h) * 16 + (wv * 2 + nt);
                    breg[nt][h] = *(const bf16x8*)(Bg + (size_t)slot * 512);
                }
            const unsigned aoff = cur * 8192u;
            #pragma unroll
            for (int rt = 0; rt < 4; ++rt) {
                const unsigned ar = aoff + (rt * 16 + l15) * 128;
                bf16x8 a0 = *(const bf16x8*)(smem + ar + kb0);
                bf16x8 a1 = *(const bf16x8*)(smem + ar + kb1);
                acc[rt][0] = __builtin_amdgcn_mfma_f32_16x16x32_bf16(a0, breg[0][0], acc[rt][0], 0, 0, 0);
                acc[rt][0] = __builtin_amdgcn_mfma_f32_16x16x32_bf16(a1, breg[0][1], acc[rt][0], 0, 0, 0);
                acc[rt][1] = __builtin_amdgcn_mfma_f32_16x16x32_bf16(a0, breg[1][0], acc[rt][1], 0, 0, 0);
                acc[rt][1] = __builtin_amdgcn_mfma_f32_16x16x32_bf16(a1, breg[1][1], acc[rt][1], 0, 0, 0);
            }
        }
        if (kt < 11)
            write_a(cur ^ 1, va[cur]);           // waits A(kt+1); newer loads keep flying
        asm volatile("s_waitcnt lgkmcnt(0)" ::: "memory");
        __builtin_amdgcn_s_barrier();
        __builtin_amdgcn_sched_barrier(0);
    }

    // ---- epilogue: tanh(+bz) . t , reduce over N ----
    // C/D layout: col = lane&15, row = (lane>>4)*4 + reg (+ rt*16)
    const float* tb = tws + (b << 8);
    float tv[2], bzv[2];
    #pragma unroll
    for (int nt = 0; nt < 2; ++nt) {
        const int col = wv * 32 + nt * 16 + l15;
        tv[nt]  = tb[col];
        bzv[nt] = bz[col];
    }
    float p[4][4];
    #pragma unroll
    for (int rt = 0; rt < 4; ++rt)
        #pragma unroll
        for (int r = 0; r < 4; ++r) {
            float s = 0.f;
            #pragma unroll
            for (int nt = 0; nt < 2; ++nt)
                s += fast_tanh(acc[rt][nt][r] + bzv[nt]) * tv[nt];
            p[rt][r] = s;
        }

    #pragma unroll
    for (int rt = 0; rt < 4; ++rt)
        #pragma unroll
        for (int r = 0; r < 4; ++r) {
            float v = p[rt][r];
            v += __shfl_xor(v, 1);
            v += __shfl_xor(v, 2);
            v += __shfl_xor(v, 4);
            v += __shfl_xor(v, 8);
            p[rt][r] = v;
        }
    float* psum = (float*)smem;   // [row 0..63][wv 0..7]; safe after final barrier
    if (l15 == 0) {
        #pragma unroll
        for (int rt = 0; rt < 4; ++rt)
            #pragma unroll
            for (int r = 0; r < 4; ++r) {
                const int rowl = rt * 16 + l4 * 4 + r;
                psum[rowl * 8 + wv] = p[rt][r];
            }
    }
    __syncthreads();
    if (tid < 64) {
        float s = 0.f;
        #pragma unroll
        for (int w = 0; w < 8; ++w) s += psum[tid * 8 + w];
        out[rowbase + tid] = s * 0.03608439182435161f;   // 1/sqrt(768)
    }
}

// ---------------------------------------------------------------------------
// softmax (in-place over d_out), one block per batch; mask applied per flag
// ---------------------------------------------------------------------------
__global__ void softmax_kernel(float* __restrict__ out,
                               const void* __restrict__ mask,
                               const int* __restrict__ flagp)
{
    const int b = blockIdx.x, tid = threadIdx.x;
    __shared__ float vals[4096];
    __shared__ float red[8];
    const int flag = *flagp;
    const int base = b << 12;
    float* po = out + base;
    float mx = -INFINITY;
    #pragma unroll
    for (int i = 0; i < 16; ++i) {
        const int z = i * 256 + tid;
        const int gi = base + z;
        bool msk;
        if (flag == 1)      msk = ((const unsigned char*)mask)[gi] != 0;
        else if (flag == 0) msk = ((const int*)mask)[gi] != 0;
        else if (flag == 2) msk = ((const float*)mask)[gi] != 0.f;
        else                msk = ((const long long*)mask)[gi] != 0;
        const float v = msk ? -INFINITY : po[z];
        vals[z] = v;
        mx = fmaxf(mx, v);
    }
    #pragma unroll
    for (int off = 32; off > 0; off >>= 1) mx = fmaxf(mx, __shfl_xor(mx, off));
    if ((tid & 63) == 0) red[tid >> 6] = mx;
    __syncthreads();
    mx = fmaxf(fmaxf(red[0], red[1]), fmaxf(red[2], red[3]));
    float s = 0.f;
    #pragma unroll
    for (int i = 0; i < 16; ++i) {
        const int z = i * 256 + tid;
        const float e = __expf(vals[z] - mx);   // -inf -> 0
        vals[z] = e;
        s += e;
    }
    #pragma unroll
    for (int off = 32; off > 0; off >>= 1) s += __shfl_xor(s, off);
    if ((tid & 63) == 0) red[4 + (tid >> 6)] = s;
    __syncthreads();
    const float inv = 1.f / (red[4] + red[5] + red[6] + red[7]);
    #pragma unroll
    for (int i = 0; i < 16; ++i) {
        const int z = i * 256 + tid;
        po[z] = vals[z] * inv;
    }
}

// ---------------------------------------------------------------------------
extern "C" void kernel_launch(void* const* d_in, const int* in_sizes, int n_in,
                              void* d_out, int out_size, void* d_ws, size_t ws_size,
                              hipStream_t stream)
{
    (void)in_sizes; (void)n_in; (void)out_size; (void)ws_size;
    const float* txt  = (const float*)d_in[0];
    const float* zone = (const float*)d_in[1];
    const void*  mask = d_in[2];
    const float* Wt   = (const float*)d_in[3];
    const float* bt   = (const float*)d_in[4];
    const float* Wz   = (const float*)d_in[5];
    const float* bz   = (const float*)d_in[6];
    float* out = (float*)d_out;
    char*  ws  = (char*)d_ws;
    float* tws           = (float*)(ws + OFF_T);
    unsigned short* wzt  = (unsigned short*)(ws + OFF_WZT);
    int*   flagp         = (int*)(ws + OFF_FLAG);
    float* mp            = (float*)(ws + OFF_MP);

    prep1_kernel<<<321, 256, 0, stream>>>(txt, Wz, mask, mp, wzt, flagp);
    prep2_kernel<<<32, 256, 0, stream>>>(mp, Wt, bt, tws);
    gemm_kernel<<<2048, 512, 0, stream>>>(zone, wzt, tws, bz, out);
    softmax_kernel<<<32, 256, 0, stream>>>(out, mask, flagp);
}

// Round 13
// 125.895 us; speedup vs baseline: 2.1426x; 2.1426x over previous
//
#include <hip/hip_runtime.h>
#include <cstdint>
#include <cstddef>

// ---------------------------------------------------------------------------
// Zoner: out = softmax( mask ? -inf : tanh(zone@Wz+bz) . tanh(mean(txt)@Wt+bt) / sqrt(768) )
// B=32 L=80 Z=4096 D=768 DO=256.  Dominant cost: 402MB zone read.
// Read-stream invariant ~3.2 TB/s across 7 axes (schedule/tile/occupancy/
// transport/address-pattern/XCD-affinity/TLP); m13's copy read-half = 3.15
// TB/s matches; fills (write-only) = 6.7. R12's forced-occupancy test spilled
// (VGPR 40, WRITE 331MB) — reverted.
// R13 = R11 + ONE change: zone loads are NON-TEMPORAL (nt flag) — tests the
// L2 allocate-on-read-miss path as the read-rate limiter.
// ---------------------------------------------------------------------------

typedef float  f32x4  __attribute__((ext_vector_type(4)));
typedef __bf16 bf16x4 __attribute__((ext_vector_type(4)));
typedef __bf16 bf16x8 __attribute__((ext_vector_type(8)));

// workspace layout (bytes)
#define OFF_T     0         // t[32][256] fp32          (32 KB)
#define OFF_WZT   32768     // WzT fragment-order bf16, 196608 elems (384 KB)
#define OFF_FLAG  425984    // mask-format flag (int)
#define OFF_MP    426240    // mean partials [32][8][768] fp32 (768 KB)

__device__ __forceinline__ float fast_tanh(float x) {
    x = fminf(15.f, fmaxf(-15.f, x));
    float e2 = __expf(2.f * x);
    return (e2 - 1.f) * __builtin_amdgcn_rcpf(e2 + 1.f);
}

// ---------------------------------------------------------------------------
// prep1: blocks 0..255   : txt mean partial sums (b = blk>>3, 10 L-slices each)
//        blocks 256..319 : Wz -> fragment-order wzt
//          wzt[((kt*2+h)*16+g)*512 + lane*8 + e] = bf16(Wz[k][n])
//          with n = g*16 + (lane&15), k = kt*64 + h*32 + (lane>>4)*8 + e.
//        block  320      : mask dtype detector -> flag {0:int32,1:bytes,2:fp32,3:int64}
// ---------------------------------------------------------------------------
__global__ void prep1_kernel(const float* __restrict__ txt,
                             const float* __restrict__ Wz,
                             const void*  __restrict__ mask,
                             float* __restrict__ mp,
                             unsigned short* __restrict__ wzt,
                             int* __restrict__ flagp)
{
    const int blk = blockIdx.x, tid = threadIdx.x;
    if (blk < 256) {
        const int b = blk >> 3, part = blk & 7;
        const float* base = txt + (size_t)(b * 80 + part * 10) * 768;
        for (int d = tid; d < 768; d += 256) {
            float s = 0.f;
            #pragma unroll
            for (int l = 0; l < 10; ++l) s += base[l * 768 + d];
            mp[(b * 8 + part) * 768 + d] = s;
        }
    } else if (blk < 320) {
        const int i0 = (blk - 256) * 3072;
        for (int it = 0; it < 12; ++it) {
            int idx  = i0 + it * 256 + tid;      // 0..196607
            int e    = idx & 7;
            int lane = (idx >> 3) & 63;
            int slot = idx >> 9;                 // (kt*2+h)*16 + g
            int kt   = slot >> 5;
            int h    = (slot >> 4) & 1;
            int g    = slot & 15;
            int n    = g * 16 + (lane & 15);
            int k    = kt * 64 + h * 32 + (lane >> 4) * 8 + e;
            __bf16 v = (__bf16)Wz[k * 256 + n];
            wzt[idx] = __builtin_bit_cast(unsigned short, v);
        }
    } else {
        // scan first 32768 bytes (valid window for every candidate dtype)
        const unsigned* mw = (const unsigned*)mask;
        unsigned f_isf = 0, f_gt = 0, f_onz = 0, f_nz = 0;
        for (int i = tid; i < 8192; i += 256) {
            unsigned w = mw[i];
            if (w == 0x3F800000u) f_isf = 1;   // float 1.0 pattern
            else if (w > 1u)      f_gt  = 1;   // packed bool bytes
            if (w) { f_nz = 1; if (i & 1) f_onz = 1; }
        }
        __shared__ unsigned r[4];
        if (tid < 4) r[tid] = 0;
        __syncthreads();
        if (f_isf) atomicOr(&r[0], 1u);
        if (f_gt)  atomicOr(&r[1], 1u);
        if (f_onz) atomicOr(&r[2], 1u);
        if (f_nz)  atomicOr(&r[3], 1u);
        __syncthreads();
        if (tid == 0) {
            int flag;
            if (r[0])        flag = 2;   // fp32 0/1
            else if (r[1])   flag = 1;   // bytes
            else if (!r[3])  flag = 1;   // all-zero: byte path is always safe
            else if (!r[2])  flag = 3;   // nonzeros but all odd words zero -> int64
            else             flag = 0;   // int32
            *flagp = flag;
        }
    }
}

// ---------------------------------------------------------------------------
// prep2: mean = sum(partials)/80 ; t[b][o] = tanh(mean @ Wt + bt)   (fp32)
// ---------------------------------------------------------------------------
__global__ void prep2_kernel(const float* __restrict__ mp,
                             const float* __restrict__ Wt,
                             const float* __restrict__ bt,
                             float* __restrict__ tws)
{
    const int b = blockIdx.x, tid = threadIdx.x;
    __shared__ float meanv[768];
    for (int d = tid; d < 768; d += 256) {
        float s = 0.f;
        #pragma unroll
        for (int p = 0; p < 8; ++p) s += mp[(b * 8 + p) * 768 + d];
        meanv[d] = s * 0.0125f;   // 1/80
    }
    __syncthreads();
    float acc = bt[tid];
    for (int d = 0; d < 768; ++d) acc = fmaf(meanv[d], Wt[d * 256 + tid], acc);
    tws[b * 256 + tid] = tanhf(acc);
}

// ---------------------------------------------------------------------------
// Fused GEMM (R7 core) + XCD-chunk swizzle + NON-TEMPORAL zone loads.
// BM=64 rows/block, N=256, K=768 (12 steps), 512 thr / 8 waves; wave wv owns
// 64 rows x cols [wv*32,+32): acc[4][2]. A: fp32->bf16 reg-staged into
// XOR-swizzled LDS (2x8KB dbuf), 2-deep reg prefetch, nt loads. B: fragment-
// order wzt, coalesced 1KB wave reads, reg dbuf (breg[kt&1]==B(kt)).
// Sync: raw s_barrier + lgkmcnt(0); vmcnt never drained.
// ---------------------------------------------------------------------------
__global__ __launch_bounds__(512, 4)
void gemm_kernel(const float* __restrict__ zone,
                 const unsigned short* __restrict__ wzt,   // fragment-order B
                 const float* __restrict__ tws,
                 const float* __restrict__ bz,
                 float* __restrict__ out)
{
    __shared__ alignas(16) unsigned char smem[16384];   // A double buffer only
    const int tid  = threadIdx.x;
    // XCD-chunk swizzle (bijective, 2048 % 8 == 0)
    const int orig = blockIdx.x;
    const int blk  = (orig & 7) * 256 + (orig >> 3);
    const int rowbase = blk << 6;          // 64 rows per block
    const int b    = blk >> 6;             // batch (64 blocks each)
    const int lane = tid & 63;
    const int wv   = tid >> 6;             // wave 0..7; cols wv*32..wv*32+31
    const int l15  = lane & 15;
    const int l4   = lane >> 4;

    // A fragment LDS addresses (rows of 128B, XOR-swizzled 16B chunks by row&7)
    const int swz = (l15 & 7) << 4;
    const int kb0 = (l4 * 16) ^ swz;             // k 0..31
    const int kb1 = (64 + l4 * 16) ^ swz;        // k 32..63

    // A staging: 1024 8B-chunks; thread t handles chunks t and t+512.
    const int sg_r0 = tid >> 4;                  // rows 0..31 (i=0) / +32 (i=1)
    const int sg_c4 = tid & 15;
    const int sg_kb = (sg_c4 * 8) ^ ((sg_r0 & 7) << 4);   // (row+32)&7 == row&7

    // B fragment base: coalesced — lane's 16B chunk within each 1KB slot
    const unsigned short* Bg = wzt + (size_t)lane * 8;

    f32x4 acc[4][2];
    #pragma unroll
    for (int i = 0; i < 4; ++i)
        #pragma unroll
        for (int j = 0; j < 2; ++j)
            acc[i][j] = f32x4{0.f, 0.f, 0.f, 0.f};

    const float* Ag = zone + (size_t)rowbase * 768;

    f32x4  va[2][2];          // A 2-deep register prefetch (fp32)
    bf16x8 breg[2][2][2];     // B double buffer [buf][nt][h]

    auto load_a = [&](int kt, f32x4* v) {
        const float* Agk = Ag + kt * 64 + sg_c4 * 4;
        // NON-TEMPORAL: zone is streamed once; don't retain in L2.
        v[0] = __builtin_nontemporal_load((const f32x4*)(Agk + (size_t)sg_r0 * 768));
        v[1] = __builtin_nontemporal_load((const f32x4*)(Agk + (size_t)(sg_r0 + 32) * 768));
    };
    auto write_a = [&](int buf, const f32x4* v) {
        #pragma unroll
        for (int i = 0; i < 2; ++i) {
            bf16x4 h = { (__bf16)v[i][0], (__bf16)v[i][1], (__bf16)v[i][2], (__bf16)v[i][3] };
            *(bf16x4*)(smem + buf * 8192 + (i * 32 + sg_r0) * 128 + sg_kb) = h;
        }
    };
    auto load_b = [&](int kt, int buf) {
        #pragma unroll
        for (int nt = 0; nt < 2; ++nt)
            #pragma unroll
            for (int h = 0; h < 2; ++h) {
                const int slot = (kt * 2 + h) * 16 + (wv * 2 + nt);
                breg[buf][nt][h] = *(const bf16x8*)(Bg + (size_t)slot * 512);
            }
    };

    // ---- prologue (invariant: va[cur]==A(kt+1), breg[kt&1]==B(kt)) ----
    load_a(0, va[1]);             // A(0) temp
    load_b(0, 0);
    load_b(1, 1);
    write_a(0, va[1]);            // compiler waits exactly for va[1]
    load_a(1, va[0]);             // A(1) stays in flight across barrier
    asm volatile("s_waitcnt lgkmcnt(0)" ::: "memory");
    __builtin_amdgcn_s_barrier();
    __builtin_amdgcn_sched_barrier(0);

    // ---- main K loop (fully unrolled; all indices compile-time) ----
    #pragma unroll
    for (int kt = 0; kt < 12; ++kt) {
        const int cur = kt & 1;
        if (kt < 10) {
            load_a(kt + 2, va[cur ^ 1]);         // A(kt+2): newest in queue
            __builtin_amdgcn_sched_barrier(0);   // pin issue at phase top
        }
        // compute: A frags from LDS[cur], B from breg[cur]
        {
            const unsigned aoff = cur * 8192u;
            #pragma unroll
            for (int rt = 0; rt < 4; ++rt) {
                const unsigned ar = aoff + (rt * 16 + l15) * 128;
                bf16x8 a0 = *(const bf16x8*)(smem + ar + kb0);
                bf16x8 a1 = *(const bf16x8*)(smem + ar + kb1);
                acc[rt][0] = __builtin_amdgcn_mfma_f32_16x16x32_bf16(a0, breg[cur][0][0], acc[rt][0], 0, 0, 0);
                acc[rt][0] = __builtin_amdgcn_mfma_f32_16x16x32_bf16(a1, breg[cur][0][1], acc[rt][0], 0, 0, 0);
                acc[rt][1] = __builtin_amdgcn_mfma_f32_16x16x32_bf16(a0, breg[cur][1][0], acc[rt][1], 0, 0, 0);
                acc[rt][1] = __builtin_amdgcn_mfma_f32_16x16x32_bf16(a1, breg[cur][1][1], acc[rt][1], 0, 0, 0);
            }
        }
        if (kt < 10)
            load_b(kt + 2, cur);                 // refill just-consumed buffer (WAR-safe)
        if (kt < 11)
            write_a(cur ^ 1, va[cur]);           // waits A(kt+1); newer loads keep flying
        asm volatile("s_waitcnt lgkmcnt(0)" ::: "memory");
        __builtin_amdgcn_s_barrier();
        __builtin_amdgcn_sched_barrier(0);
    }

    // ---- epilogue: tanh(+bz) . t , reduce over N ----
    // C/D layout: col = lane&15, row = (lane>>4)*4 + reg (+ rt*16)
    const float* tb = tws + (b << 8);
    float tv[2], bzv[2];
    #pragma unroll
    for (int nt = 0; nt < 2; ++nt) {
        const int col = wv * 32 + nt * 16 + l15;
        tv[nt]  = tb[col];
        bzv[nt] = bz[col];
    }
    float p[4][4];
    #pragma unroll
    for (int rt = 0; rt < 4; ++rt)
        #pragma unroll
        for (int r = 0; r < 4; ++r) {
            float s = 0.f;
            #pragma unroll
            for (int nt = 0; nt < 2; ++nt)
                s += fast_tanh(acc[rt][nt][r] + bzv[nt]) * tv[nt];
            p[rt][r] = s;
        }

    #pragma unroll
    for (int rt = 0; rt < 4; ++rt)
        #pragma unroll
        for (int r = 0; r < 4; ++r) {
            float v = p[rt][r];
            v += __shfl_xor(v, 1);
            v += __shfl_xor(v, 2);
            v += __shfl_xor(v, 4);
            v += __shfl_xor(v, 8);
            p[rt][r] = v;
        }
    float* psum = (float*)smem;   // [row 0..63][wv 0..7]; safe after final barrier
    if (l15 == 0) {
        #pragma unroll
        for (int rt = 0; rt < 4; ++rt)
            #pragma unroll
            for (int r = 0; r < 4; ++r) {
                const int rowl = rt * 16 + l4 * 4 + r;
                psum[rowl * 8 + wv] = p[rt][r];
            }
    }
    __syncthreads();
    if (tid < 64) {
        float s = 0.f;
        #pragma unroll
        for (int w = 0; w < 8; ++w) s += psum[tid * 8 + w];
        out[rowbase + tid] = s * 0.03608439182435161f;   // 1/sqrt(768)
    }
}

// ---------------------------------------------------------------------------
// softmax (in-place over d_out), one block per batch; mask applied per flag
// ---------------------------------------------------------------------------
__global__ void softmax_kernel(float* __restrict__ out,
                               const void* __restrict__ mask,
                               const int* __restrict__ flagp)
{
    const int b = blockIdx.x, tid = threadIdx.x;
    __shared__ float vals[4096];
    __shared__ float red[8];
    const int flag = *flagp;
    const int base = b << 12;
    float* po = out + base;
    float mx = -INFINITY;
    #pragma unroll
    for (int i = 0; i < 16; ++i) {
        const int z = i * 256 + tid;
        const int gi = base + z;
        bool msk;
        if (flag == 1)      msk = ((const unsigned char*)mask)[gi] != 0;
        else if (flag == 0) msk = ((const int*)mask)[gi] != 0;
        else if (flag == 2) msk = ((const float*)mask)[gi] != 0.f;
        else                msk = ((const long long*)mask)[gi] != 0;
        const float v = msk ? -INFINITY : po[z];
        vals[z] = v;
        mx = fmaxf(mx, v);
    }
    #pragma unroll
    for (int off = 32; off > 0; off >>= 1) mx = fmaxf(mx, __shfl_xor(mx, off));
    if ((tid & 63) == 0) red[tid >> 6] = mx;
    __syncthreads();
    mx = fmaxf(fmaxf(red[0], red[1]), fmaxf(red[2], red[3]));
    float s = 0.f;
    #pragma unroll
    for (int i = 0; i < 16; ++i) {
        const int z = i * 256 + tid;
        const float e = __expf(vals[z] - mx);   // -inf -> 0
        vals[z] = e;
        s += e;
    }
    #pragma unroll
    for (int off = 32; off > 0; off >>= 1) s += __shfl_xor(s, off);
    if ((tid & 63) == 0) red[4 + (tid >> 6)] = s;
    __syncthreads();
    const float inv = 1.f / (red[4] + red[5] + red[6] + red[7]);
    #pragma unroll
    for (int i = 0; i < 16; ++i) {
        const int z = i * 256 + tid;
        po[z] = vals[z] * inv;
    }
}

// ---------------------------------------------------------------------------
extern "C" void kernel_launch(void* const* d_in, const int* in_sizes, int n_in,
                              void* d_out, int out_size, void* d_ws, size_t ws_size,
                              hipStream_t stream)
{
    (void)in_sizes; (void)n_in; (void)out_size; (void)ws_size;
    const float* txt  = (const float*)d_in[0];
    const float* zone = (const float*)d_in[1];
    const void*  mask = d_in[2];
    const float* Wt   = (const float*)d_in[3];
    const float* bt   = (const float*)d_in[4];
    const float* Wz   = (const float*)d_in[5];
    const float* bz   = (const float*)d_in[6];
    float* out = (float*)d_out;
    char*  ws  = (char*)d_ws;
    float* tws           = (float*)(ws + OFF_T);
    unsigned short* wzt  = (unsigned short*)(ws + OFF_WZT);
    int*   flagp         = (int*)(ws + OFF_FLAG);
    float* mp            = (float*)(ws + OFF_MP);

    prep1_kernel<<<321, 256, 0, stream>>>(txt, Wz, mask, mp, wzt, flagp);
    prep2_kernel<<<32, 256, 0, stream>>>(mp, Wt, bt, tws);
    gemm_kernel<<<2048, 512, 0, stream>>>(zone, wzt, tws, bz, out);
    softmax_kernel<<<32, 256, 0, stream>>>(out, mask, flagp);
}

// Round 14
// 122.002 us; speedup vs baseline: 2.2109x; 1.0319x over previous
//
#include <hip/hip_runtime.h>
#include <cstdint>
#include <cstddef>

// ---------------------------------------------------------------------------
// Zoner: out = softmax( mask ? -inf : tanh(zone@Wz+bz) . tanh(mean(txt)@Wt+bt) / sqrt(768) )
// B=32 L=80 Z=4096 D=768 DO=256.  Dominant cost: 402MB zone read.
// R13 BREAKTHROUGH: non-temporal zone loads 152.1 -> 125.9us. The ~3.2 TB/s
// read invariant was the L2/L3 allocate-on-read-miss path; nt bypasses it
// (fills 6.7 TB/s = no-allocate writes; copy read-half 3.15 matches).
// R14 = R13 GEMM byte-identical + prep1/prep2 fused into ONE dispatch
// (mean->t computed directly, no mp round-trip; this prep ran correctly in
// R10). Softmax stays a separate kernel (R10 lesson: no device fences /
// cross-GEMM fusion). 3 launches instead of 4.
// VGPR note: GEMM compiles to ~60 VGPR — just under the 64 occupancy cliff
// (m69). Do NOT deepen prefetch (would cross it).
// ---------------------------------------------------------------------------

typedef float  f32x4  __attribute__((ext_vector_type(4)));
typedef __bf16 bf16x4 __attribute__((ext_vector_type(4)));
typedef __bf16 bf16x8 __attribute__((ext_vector_type(8)));

// workspace layout (bytes)
#define OFF_T     0         // t[32][256] fp32          (32 KB)
#define OFF_WZT   32768     // WzT fragment-order bf16, 196608 elems (384 KB)
#define OFF_FLAG  425984    // mask-format flag (int)

__device__ __forceinline__ float fast_tanh(float x) {
    x = fminf(15.f, fmaxf(-15.f, x));
    float e2 = __expf(2.f * x);
    return (e2 - 1.f) * __builtin_amdgcn_rcpf(e2 + 1.f);
}

// ---------------------------------------------------------------------------
// prep: blocks 0..31  : mean over txt[b] -> t[b] = tanh(mean@Wt+bt)
//       blocks 32..95 : Wz -> fragment-order wzt
//         wzt[((kt*2+h)*16+g)*512 + lane*8 + e] = bf16(Wz[k][n]),
//         n = g*16+(lane&15), k = kt*64+h*32+(lane>>4)*8+e.
//       block  96     : mask dtype detector -> flag {0:int32,1:bytes,2:fp32,3:int64}
// ---------------------------------------------------------------------------
__global__ void prep_kernel(const float* __restrict__ txt,
                            const float* __restrict__ Wz,
                            const float* __restrict__ Wt,
                            const float* __restrict__ bt,
                            const void*  __restrict__ mask,
                            float* __restrict__ tws,
                            unsigned short* __restrict__ wzt,
                            int* __restrict__ flagp)
{
    const int blk = blockIdx.x, tid = threadIdx.x;
    if (blk < 32) {
        __shared__ float meanv[768];
        const float* base = txt + (size_t)blk * 80 * 768;
        for (int d = tid; d < 768; d += 256) {
            float s = 0.f;
            for (int l = 0; l < 80; ++l) s += base[l * 768 + d];
            meanv[d] = s * 0.0125f;   // 1/80
        }
        __syncthreads();
        float acc = bt[tid];
        for (int d = 0; d < 768; ++d) acc = fmaf(meanv[d], Wt[d * 256 + tid], acc);
        tws[blk * 256 + tid] = tanhf(acc);
    } else if (blk < 96) {
        const int i0 = (blk - 32) * 3072;
        for (int it = 0; it < 12; ++it) {
            int idx  = i0 + it * 256 + tid;      // 0..196607
            int e    = idx & 7;
            int lane = (idx >> 3) & 63;
            int slot = idx >> 9;                 // (kt*2+h)*16 + g
            int kt   = slot >> 5;
            int h    = (slot >> 4) & 1;
            int g    = slot & 15;
            int n    = g * 16 + (lane & 15);
            int k    = kt * 64 + h * 32 + (lane >> 4) * 8 + e;
            __bf16 v = (__bf16)Wz[k * 256 + n];
            wzt[idx] = __builtin_bit_cast(unsigned short, v);
        }
    } else {
        // scan first 32768 bytes (valid window for every candidate dtype)
        const unsigned* mw = (const unsigned*)mask;
        unsigned f_isf = 0, f_gt = 0, f_onz = 0, f_nz = 0;
        for (int i = tid; i < 8192; i += 256) {
            unsigned w = mw[i];
            if (w == 0x3F800000u) f_isf = 1;   // float 1.0 pattern
            else if (w > 1u)      f_gt  = 1;   // packed bool bytes
            if (w) { f_nz = 1; if (i & 1) f_onz = 1; }
        }
        __shared__ unsigned r[4];
        if (tid < 4) r[tid] = 0;
        __syncthreads();
        if (f_isf) atomicOr(&r[0], 1u);
        if (f_gt)  atomicOr(&r[1], 1u);
        if (f_onz) atomicOr(&r[2], 1u);
        if (f_nz)  atomicOr(&r[3], 1u);
        __syncthreads();
        if (tid == 0) {
            int flag;
            if (r[0])        flag = 2;   // fp32 0/1
            else if (r[1])   flag = 1;   // bytes
            else if (!r[3])  flag = 1;   // all-zero: byte path is always safe
            else if (!r[2])  flag = 3;   // nonzeros but all odd words zero -> int64
            else             flag = 0;   // int32
            *flagp = flag;
        }
    }
}

// ---------------------------------------------------------------------------
// Fused GEMM (R13, byte-identical): XCD-chunk swizzle + NON-TEMPORAL zone
// loads. BM=64, N=256, K=768 (12 steps), 512 thr / 8 waves; wave wv owns
// 64 rows x cols [wv*32,+32): acc[4][2]. A: fp32->bf16 reg-staged into
// XOR-swizzled LDS (2x8KB dbuf), 2-deep reg prefetch, nt loads. B: fragment-
// order wzt, coalesced 1KB wave reads, reg dbuf (breg[kt&1]==B(kt)).
// Sync: raw s_barrier + lgkmcnt(0); vmcnt never drained.
// ---------------------------------------------------------------------------
__global__ __launch_bounds__(512, 4)
void gemm_kernel(const float* __restrict__ zone,
                 const unsigned short* __restrict__ wzt,   // fragment-order B
                 const float* __restrict__ tws,
                 const float* __restrict__ bz,
                 float* __restrict__ out)
{
    __shared__ alignas(16) unsigned char smem[16384];   // A double buffer only
    const int tid  = threadIdx.x;
    // XCD-chunk swizzle (bijective, 2048 % 8 == 0)
    const int orig = blockIdx.x;
    const int blk  = (orig & 7) * 256 + (orig >> 3);
    const int rowbase = blk << 6;          // 64 rows per block
    const int b    = blk >> 6;             // batch (64 blocks each)
    const int lane = tid & 63;
    const int wv   = tid >> 6;             // wave 0..7; cols wv*32..wv*32+31
    const int l15  = lane & 15;
    const int l4   = lane >> 4;

    // A fragment LDS addresses (rows of 128B, XOR-swizzled 16B chunks by row&7)
    const int swz = (l15 & 7) << 4;
    const int kb0 = (l4 * 16) ^ swz;             // k 0..31
    const int kb1 = (64 + l4 * 16) ^ swz;        // k 32..63

    // A staging: 1024 8B-chunks; thread t handles chunks t and t+512.
    const int sg_r0 = tid >> 4;                  // rows 0..31 (i=0) / +32 (i=1)
    const int sg_c4 = tid & 15;
    const int sg_kb = (sg_c4 * 8) ^ ((sg_r0 & 7) << 4);   // (row+32)&7 == row&7

    // B fragment base: coalesced — lane's 16B chunk within each 1KB slot
    const unsigned short* Bg = wzt + (size_t)lane * 8;

    f32x4 acc[4][2];
    #pragma unroll
    for (int i = 0; i < 4; ++i)
        #pragma unroll
        for (int j = 0; j < 2; ++j)
            acc[i][j] = f32x4{0.f, 0.f, 0.f, 0.f};

    const float* Ag = zone + (size_t)rowbase * 768;

    f32x4  va[2][2];          // A 2-deep register prefetch (fp32)
    bf16x8 breg[2][2][2];     // B double buffer [buf][nt][h]

    auto load_a = [&](int kt, f32x4* v) {
        const float* Agk = Ag + kt * 64 + sg_c4 * 4;
        // NON-TEMPORAL: zone is streamed once; don't allocate in L2/L3.
        v[0] = __builtin_nontemporal_load((const f32x4*)(Agk + (size_t)sg_r0 * 768));
        v[1] = __builtin_nontemporal_load((const f32x4*)(Agk + (size_t)(sg_r0 + 32) * 768));
    };
    auto write_a = [&](int buf, const f32x4* v) {
        #pragma unroll
        for (int i = 0; i < 2; ++i) {
            bf16x4 h = { (__bf16)v[i][0], (__bf16)v[i][1], (__bf16)v[i][2], (__bf16)v[i][3] };
            *(bf16x4*)(smem + buf * 8192 + (i * 32 + sg_r0) * 128 + sg_kb) = h;
        }
    };
    auto load_b = [&](int kt, int buf) {
        #pragma unroll
        for (int nt = 0; nt < 2; ++nt)
            #pragma unroll
            for (int h = 0; h < 2; ++h) {
                const int slot = (kt * 2 + h) * 16 + (wv * 2 + nt);
                breg[buf][nt][h] = *(const bf16x8*)(Bg + (size_t)slot * 512);
            }
    };

    // ---- prologue (invariant: va[cur]==A(kt+1), breg[kt&1]==B(kt)) ----
    load_a(0, va[1]);             // A(0) temp
    load_b(0, 0);
    load_b(1, 1);
    write_a(0, va[1]);            // compiler waits exactly for va[1]
    load_a(1, va[0]);             // A(1) stays in flight across barrier
    asm volatile("s_waitcnt lgkmcnt(0)" ::: "memory");
    __builtin_amdgcn_s_barrier();
    __builtin_amdgcn_sched_barrier(0);

    // ---- main K loop (fully unrolled; all indices compile-time) ----
    #pragma unroll
    for (int kt = 0; kt < 12; ++kt) {
        const int cur = kt & 1;
        if (kt < 10) {
            load_a(kt + 2, va[cur ^ 1]);         // A(kt+2): newest in queue
            __builtin_amdgcn_sched_barrier(0);   // pin issue at phase top
        }
        // compute: A frags from LDS[cur], B from breg[cur]
        {
            const unsigned aoff = cur * 8192u;
            #pragma unroll
            for (int rt = 0; rt < 4; ++rt) {
                const unsigned ar = aoff + (rt * 16 + l15) * 128;
                bf16x8 a0 = *(const bf16x8*)(smem + ar + kb0);
                bf16x8 a1 = *(const bf16x8*)(smem + ar + kb1);
                acc[rt][0] = __builtin_amdgcn_mfma_f32_16x16x32_bf16(a0, breg[cur][0][0], acc[rt][0], 0, 0, 0);
                acc[rt][0] = __builtin_amdgcn_mfma_f32_16x16x32_bf16(a1, breg[cur][0][1], acc[rt][0], 0, 0, 0);
                acc[rt][1] = __builtin_amdgcn_mfma_f32_16x16x32_bf16(a0, breg[cur][1][0], acc[rt][1], 0, 0, 0);
                acc[rt][1] = __builtin_amdgcn_mfma_f32_16x16x32_bf16(a1, breg[cur][1][1], acc[rt][1], 0, 0, 0);
            }
        }
        if (kt < 10)
            load_b(kt + 2, cur);                 // refill just-consumed buffer (WAR-safe)
        if (kt < 11)
            write_a(cur ^ 1, va[cur]);           // waits A(kt+1); newer loads keep flying
        asm volatile("s_waitcnt lgkmcnt(0)" ::: "memory");
        __builtin_amdgcn_s_barrier();
        __builtin_amdgcn_sched_barrier(0);
    }

    // ---- epilogue: tanh(+bz) . t , reduce over N ----
    // C/D layout: col = lane&15, row = (lane>>4)*4 + reg (+ rt*16)
    const float* tb = tws + (b << 8);
    float tv[2], bzv[2];
    #pragma unroll
    for (int nt = 0; nt < 2; ++nt) {
        const int col = wv * 32 + nt * 16 + l15;
        tv[nt]  = tb[col];
        bzv[nt] = bz[col];
    }
    float p[4][4];
    #pragma unroll
    for (int rt = 0; rt < 4; ++rt)
        #pragma unroll
        for (int r = 0; r < 4; ++r) {
            float s = 0.f;
            #pragma unroll
            for (int nt = 0; nt < 2; ++nt)
                s += fast_tanh(acc[rt][nt][r] + bzv[nt]) * tv[nt];
            p[rt][r] = s;
        }

    #pragma unroll
    for (int rt = 0; rt < 4; ++rt)
        #pragma unroll
        for (int r = 0; r < 4; ++r) {
            float v = p[rt][r];
            v += __shfl_xor(v, 1);
            v += __shfl_xor(v, 2);
            v += __shfl_xor(v, 4);
            v += __shfl_xor(v, 8);
            p[rt][r] = v;
        }
    float* psum = (float*)smem;   // [row 0..63][wv 0..7]; safe after final barrier
    if (l15 == 0) {
        #pragma unroll
        for (int rt = 0; rt < 4; ++rt)
            #pragma unroll
            for (int r = 0; r < 4; ++r) {
                const int rowl = rt * 16 + l4 * 4 + r;
                psum[rowl * 8 + wv] = p[rt][r];
            }
    }
    __syncthreads();
    if (tid < 64) {
        float s = 0.f;
        #pragma unroll
        for (int w = 0; w < 8; ++w) s += psum[tid * 8 + w];
        out[rowbase + tid] = s * 0.03608439182435161f;   // 1/sqrt(768)
    }
}

// ---------------------------------------------------------------------------
// softmax (in-place over d_out), one block per batch; mask applied per flag
// ---------------------------------------------------------------------------
__global__ void softmax_kernel(float* __restrict__ out,
                               const void* __restrict__ mask,
                               const int* __restrict__ flagp)
{
    const int b = blockIdx.x, tid = threadIdx.x;
    __shared__ float vals[4096];
    __shared__ float red[8];
    const int flag = *flagp;
    const int base = b << 12;
    float* po = out + base;
    float mx = -INFINITY;
    #pragma unroll
    for (int i = 0; i < 16; ++i) {
        const int z = i * 256 + tid;
        const int gi = base + z;
        bool msk;
        if (flag == 1)      msk = ((const unsigned char*)mask)[gi] != 0;
        else if (flag == 0) msk = ((const int*)mask)[gi] != 0;
        else if (flag == 2) msk = ((const float*)mask)[gi] != 0.f;
        else                msk = ((const long long*)mask)[gi] != 0;
        const float v = msk ? -INFINITY : po[z];
        vals[z] = v;
        mx = fmaxf(mx, v);
    }
    #pragma unroll
    for (int off = 32; off > 0; off >>= 1) mx = fmaxf(mx, __shfl_xor(mx, off));
    if ((tid & 63) == 0) red[tid >> 6] = mx;
    __syncthreads();
    mx = fmaxf(fmaxf(red[0], red[1]), fmaxf(red[2], red[3]));
    float s = 0.f;
    #pragma unroll
    for (int i = 0; i < 16; ++i) {
        const int z = i * 256 + tid;
        const float e = __expf(vals[z] - mx);   // -inf -> 0
        vals[z] = e;
        s += e;
    }
    #pragma unroll
    for (int off = 32; off > 0; off >>= 1) s += __shfl_xor(s, off);
    if ((tid & 63) == 0) red[4 + (tid >> 6)] = s;
    __syncthreads();
    const float inv = 1.f / (red[4] + red[5] + red[6] + red[7]);
    #pragma unroll
    for (int i = 0; i < 16; ++i) {
        const int z = i * 256 + tid;
        po[z] = vals[z] * inv;
    }
}

// ---------------------------------------------------------------------------
extern "C" void kernel_launch(void* const* d_in, const int* in_sizes, int n_in,
                              void* d_out, int out_size, void* d_ws, size_t ws_size,
                              hipStream_t stream)
{
    (void)in_sizes; (void)n_in; (void)out_size; (void)ws_size;
    const float* txt  = (const float*)d_in[0];
    const float* zone = (const float*)d_in[1];
    const void*  mask = d_in[2];
    const float* Wt   = (const float*)d_in[3];
    const float* bt   = (const float*)d_in[4];
    const float* Wz   = (const float*)d_in[5];
    const float* bz   = (const float*)d_in[6];
    float* out = (float*)d_out;
    char*  ws  = (char*)d_ws;
    float* tws           = (float*)(ws + OFF_T);
    unsigned short* wzt  = (unsigned short*)(ws + OFF_WZT);
    int*   flagp         = (int*)(ws + OFF_FLAG);

    prep_kernel<<<97, 256, 0, stream>>>(txt, Wz, Wt, bt, mask, tws, wzt, flagp);
    gemm_kernel<<<2048, 512, 0, stream>>>(zone, wzt, tws, bz, out);
    softmax_kernel<<<32, 256, 0, stream>>>(out, mask, flagp);
}